// Round 20
// baseline (426.650 us; speedup 1.0000x reference)
//
#include <hip/hip_runtime.h>
#include <hip/hip_bf16.h>
#include <math.h>

#define ISZ 256
#define KSEL 31      // keep top-(K+1) = 31
#define CMIN 64      // min candidate count
#define CEXIT 192    // bisection-fallback window top
#define NCAND 320    // candidate cap
#define NSEL 64      // slow-path fp64 prefilter size
#define NBL 64       // borderline cap
#define WIN 4e-3f    // borderline half-width (>= 2x stored-sim error, ~13 sigma)
#define ZSTAT 2.25f  // thr = mean + ZSTAT*sd (~120 cands)

typedef __attribute__((ext_vector_type(8))) short bf16x8;
typedef __attribute__((ext_vector_type(4))) float f32x4;

__device__ __forceinline__ double h64_of(float f, float w0, float w1) {
    return fmax((double)f * (double)w0, 0.0) * (double)w1;
}

// ---------------- fast zero fill (replaces slow runtime 400MB fill) ----------------
__global__ __launch_bounds__(256) void zero_out(float4* __restrict__ p, size_t n4) {
    size_t i = (size_t)blockIdx.x * 256 + threadIdx.x;
    size_t stride = (size_t)gridDim.x * 256;
    float4 z = make_float4(0.f, 0.f, 0.f, 0.f);
    for (; i < n4; i += stride) p[i] = z;
}

// ---------------- embedding (proven verbatim) ----------------
__global__ __launch_bounds__(256) void emb_kernel(const float* __restrict__ F,
                                                  const float* __restrict__ w0,
                                                  const float* __restrict__ w1,
                                                  __hip_bfloat16* __restrict__ Eb,
                                                  double* __restrict__ snorm,
                                                  int n) {
    int row = blockIdx.x;
    int t = threadIdx.x;
    float f = F[(size_t)row * ISZ + t];
    double h64 = h64_of(f, w0[t], w1[t]);
    double ss = h64 * h64;
#pragma unroll
    for (int off = 32; off; off >>= 1) ss += __shfl_down(ss, off);
    __shared__ double red[4];
    if ((t & 63) == 0) red[t >> 6] = ss;
    __syncthreads();
    double tot = red[0] + red[1] + red[2] + red[3];
    double s = fmax(sqrt(tot), 1e-12);
    if (t == 0) snorm[row] = s;
    Eb[(size_t)row * ISZ + t] = __float2bfloat16((float)(h64 / s));
}

// ---------------- symmetric MFMA gemm (R17/R19 proven, verbatim) ----------------
__global__ __launch_bounds__(256) void gemm_mfma(const __hip_bfloat16* __restrict__ Eb,
                                                 float* __restrict__ S, int n) {
    int bx = blockIdx.x, by = blockIdx.y;
    if (bx < by) return;
    __shared__ float lds[4][64][65];
    int row0 = by * 128, col0 = bx * 128;
    int tid = threadIdx.x, lane = tid & 63, wid = tid >> 6;
    int wr = wid >> 1, wc = wid & 1;
    int rbase = row0 + wr * 64 + (lane & 15);
    int cbase = col0 + wc * 64 + (lane & 15);
    int kg2 = ((lane >> 4) * 8) * 2;
    const char* Ep = (const char*)Eb;
    unsigned aoff[4], boff[4];
#pragma unroll
    for (int i = 0; i < 4; ++i) {
        aoff[i] = (unsigned)min(rbase + i * 16, n - 1) * (ISZ * 2) + kg2;
        boff[i] = (unsigned)min(cbase + i * 16, n - 1) * (ISZ * 2) + kg2;
    }
    f32x4 acc[4][4] = {};
#pragma unroll
    for (int kt = 0; kt < ISZ; kt += 32) {
        bf16x8 a[4], b[4];
#pragma unroll
        for (int i = 0; i < 4; ++i) a[i] = *(const bf16x8*)(Ep + aoff[i] + kt * 2);
#pragma unroll
        for (int j = 0; j < 4; ++j) b[j] = *(const bf16x8*)(Ep + boff[j] + kt * 2);
#pragma unroll
        for (int i = 0; i < 4; ++i)
#pragma unroll
            for (int j = 0; j < 4; ++j)
                acc[i][j] = __builtin_amdgcn_mfma_f32_16x16x32_bf16(a[i], b[j], acc[i][j], 0, 0, 0);
    }
    float (*T)[65] = lds[wid];   // wave-private
#pragma unroll
    for (int i = 0; i < 4; ++i)
#pragma unroll
        for (int j = 0; j < 4; ++j)
#pragma unroll
            for (int r = 0; r < 4; ++r)
                T[(lane >> 4) * 4 + i * 16 + r][(lane & 15) + j * 16] = acc[i][j][r];
    int gr0 = row0 + wr * 64;
    int gc0 = col0 + wc * 64;
    int c4 = (lane & 15) * 4;
#pragma unroll
    for (int p = 0; p < 16; ++p) {
        int r = p * 4 + (lane >> 4);
        int gr = gr0 + r;
        if (gr >= n) continue;
        int gc = gc0 + c4;
        float4 w = make_float4(T[r][c4], T[r][c4 + 1], T[r][c4 + 2], T[r][c4 + 3]);
        if (gc + 3 < n) {
            *(float4*)&S[(size_t)gr * n + gc] = w;
        } else {
            float wa[4] = {w.x, w.y, w.z, w.w};
#pragma unroll
            for (int q = 0; q < 4; ++q)
                if (gc + q < n) S[(size_t)gr * n + gc + q] = wa[q];
        }
    }
    if (bx > by) {
#pragma unroll
        for (int p = 0; p < 16; ++p) {
            int rp = p * 4 + (lane >> 4);
            int gr2 = gc0 + rp;
            if (gr2 >= n) continue;
            int gc2 = gr0 + c4;
            float4 w = make_float4(T[c4][rp], T[c4 + 1][rp], T[c4 + 2][rp], T[c4 + 3][rp]);
            if (gc2 + 3 < n) {
                *(float4*)&S[(size_t)gr2 * n + gc2] = w;
            } else {
                float wa[4] = {w.x, w.y, w.z, w.w};
#pragma unroll
                for (int q = 0; q < 4; ++q)
                    if (gc2 + q < n) S[(size_t)gr2 * n + gc2 + q] = wa[q];
            }
        }
    }
}

// R19-proven topk (verbatim): stats thr -> collect -> stored lex rank ->
// borderline-band fp64 -> exact rank -> patches. PATCHONLY: d_out pre-zeroed.
template <bool PATCHONLY>
__global__ __launch_bounds__(256) void topk_mask(const float* SIM, float* OUT,
                                                 const float* __restrict__ F,
                                                 const float* __restrict__ W0,
                                                 const float* __restrict__ W1,
                                                 const double* __restrict__ snorm,
                                                 int n) {
    __shared__ unsigned flags[320];
    __shared__ float redf[8];
    __shared__ int redi[4];
    __shared__ int cand_idx[NCAND];
    __shared__ float csim[NCAND];
    __shared__ int selc[NSEL];
    __shared__ int blist[NBL];
    __shared__ double cand_val[NSEL];
    __shared__ int rankarr[NSEL];
    __shared__ int ncand, nhi_s, nbl_s;
    __shared__ float s31_s;
    int row = blockIdx.x;
    int tid = threadIdx.x;
    int lane = tid & 63, wid = tid >> 6;
    const float* simp = SIM + (size_t)row * n;
    float* outp = OUT + (size_t)row * n;

    float v[40];
#pragma unroll
    for (int s = 0; s < 10; ++s) {
        int e = 4 * tid + 1024 * s;
        if (e < n) {
            float4 w = *(const float4*)(simp + e);
            v[s * 4 + 0] = w.x; v[s * 4 + 1] = w.y;
            v[s * 4 + 2] = w.z; v[s * 4 + 3] = w.w;
        } else {
#pragma unroll
            for (int q = 0; q < 4; ++q) v[s * 4 + q] = -1e30f;
        }
    }
    if constexpr (!PATCHONLY)
        for (int q = tid; q < 320; q += 256) flags[q] = 0;
    if (tid == 0) { ncand = 0; nhi_s = 0; nbl_s = 0; }
    __syncthreads();

    {
        float s1 = 0.0f, s2 = 0.0f;
#pragma unroll
        for (int s = 0; s < 10; ++s) {
            int e = 4 * tid + 1024 * s;
            if (e < n) {
#pragma unroll
                for (int j = 0; j < 4; ++j) { float x = v[s * 4 + j]; s1 += x; s2 += x * x; }
            }
        }
#pragma unroll
        for (int off = 32; off; off >>= 1) { s1 += __shfl_down(s1, off); s2 += __shfl_down(s2, off); }
        if (lane == 0) { redf[wid] = s1; redf[wid + 4] = s2; }
        __syncthreads();
        if (tid == 0) {
            float S1 = redf[0] + redf[1] + redf[2] + redf[3];
            float S2 = redf[4] + redf[5] + redf[6] + redf[7];
            float mean = S1 / (float)n;
            float var = fmaxf(S2 / (float)n - mean * mean, 1e-12f);
            s31_s = mean + ZSTAT * sqrtf(var);
        }
        __syncthreads();
    }
    float thr = s31_s;

    auto blockcount = [&](float t) -> int {
        int c = 0;
#pragma unroll
        for (int q = 0; q < 40; ++q) c += (v[q] >= t) ? 1 : 0;
#pragma unroll
        for (int off = 32; off; off >>= 1) c += __shfl_down(c, off);
        if (lane == 0) redi[wid] = c;
        __syncthreads();
        int tot = redi[0] + redi[1] + redi[2] + redi[3];
        __syncthreads();
        return tot;
    };
    auto collect = [&](float t) {
#pragma unroll
        for (int s = 0; s < 10; ++s) {
            int e = 4 * tid + 1024 * s;
#pragma unroll
            for (int j = 0; j < 4; ++j) {
                float x = v[s * 4 + j];
                if (x >= t) {
                    int pos = atomicAdd(&ncand, 1);
                    if (pos < NCAND) { cand_idx[pos] = e + j; csim[pos] = x; }
                }
            }
        }
        __syncthreads();
    };

    collect(thr);
    if (ncand < CMIN || ncand > NCAND) {
        __syncthreads();
        if (tid == 0) ncand = 0;
        __syncthreads();
        float lo = 0.0f, hi = 0.75f;
        thr = 0.0f;
        bool found = false;
        for (int it = 0; it < 30 && !found; ++it) {
            float mid = 0.5f * (lo + hi);
            int c = blockcount(mid);
            if (c >= CMIN && c <= CEXIT) { thr = mid; found = true; }
            else if (c >= CMIN) lo = mid;
            else hi = mid;
        }
        if (!found) thr = lo;
        collect(thr);
    }
    int m = min(ncand, NCAND);

    for (int c = tid; c < m; c += 256) {
        float mys = csim[c]; int myi = cand_idx[c]; int r = 0;
        for (int j = 0; j < m; ++j) {
            float vj = csim[j];
            r += (vj > mys || (vj == mys && cand_idx[j] < myi)) ? 1 : 0;
        }
        if (r < NSEL) selc[r] = c;
        if (r == KSEL - 1) s31_s = mys;
    }
    __syncthreads();
    float s31 = s31_s;

    for (int c = tid; c < m; c += 256) {
        float sc = csim[c];
        if (sc > s31 + WIN) atomicAdd(&nhi_s, 1);
        else if (sc >= s31 - WIN) { int p = atomicAdd(&nbl_s, 1); if (p < NBL) blist[p] = c; }
    }
    __syncthreads();
    int nhi = nhi_s, nblv = nbl_s;
    bool fastB = (nblv <= NBL);
    int mm = fastB ? nblv : min(m, NSEL);
    int kneed = KSEL - nhi;

    double hr[4];
    float w0e[4], w1e[4];
#pragma unroll
    for (int r = 0; r < 4; ++r) {
        int e = lane + 64 * r;
        w0e[r] = W0[e];
        w1e[r] = W1[e];
        hr[r] = h64_of(F[(size_t)row * ISZ + e], w0e[r], w1e[r]);
    }
    double srow = snorm[row];
    for (int s = wid * 4; s < mm; s += 16) {
        int l0 = fastB ? blist[s] : selc[s];
        int l1 = fastB ? blist[min(s + 1, mm - 1)] : selc[min(s + 1, mm - 1)];
        int l2 = fastB ? blist[min(s + 2, mm - 1)] : selc[min(s + 2, mm - 1)];
        int l3 = fastB ? blist[min(s + 3, mm - 1)] : selc[min(s + 3, mm - 1)];
        int j0 = cand_idx[l0], j1 = cand_idx[l1], j2 = cand_idx[l2], j3 = cand_idx[l3];
        double a0 = 0.0, a1 = 0.0, a2 = 0.0, a3 = 0.0;
#pragma unroll
        for (int r = 0; r < 4; ++r) {
            int e = lane + 64 * r;
            float f0 = F[(size_t)j0 * ISZ + e];
            float f1 = F[(size_t)j1 * ISZ + e];
            float f2 = F[(size_t)j2 * ISZ + e];
            float f3 = F[(size_t)j3 * ISZ + e];
            a0 += hr[r] * h64_of(f0, w0e[r], w1e[r]);
            a1 += hr[r] * h64_of(f1, w0e[r], w1e[r]);
            a2 += hr[r] * h64_of(f2, w0e[r], w1e[r]);
            a3 += hr[r] * h64_of(f3, w0e[r], w1e[r]);
        }
#pragma unroll
        for (int off = 32; off; off >>= 1) {
            a0 += __shfl_down(a0, off);
            a1 += __shfl_down(a1, off);
            a2 += __shfl_down(a2, off);
            a3 += __shfl_down(a3, off);
        }
        if (lane == 0) {
            cand_val[s] = a0 / (srow * snorm[j0]);
            if (s + 1 < mm) cand_val[s + 1] = a1 / (srow * snorm[j1]);
            if (s + 2 < mm) cand_val[s + 2] = a2 / (srow * snorm[j2]);
            if (s + 3 < mm) cand_val[s + 3] = a3 / (srow * snorm[j3]);
        }
    }
    __syncthreads();

    int keepthr = fastB ? kneed : KSEL;
    for (int s2 = tid; s2 < mm; s2 += 256) {
        int li = fastB ? blist[s2] : selc[s2];
        double vv = cand_val[s2];
        int idx = cand_idx[li];
        int rank = 0;
        for (int j2 = 0; j2 < mm; ++j2) {
            int lj = fastB ? blist[j2] : selc[j2];
            double vj = cand_val[j2];
            rank += (vj > vv || (vj == vv && cand_idx[lj] < idx)) ? 1 : 0;
        }
        rankarr[s2] = rank;
        if constexpr (!PATCHONLY) {
            if (rank < keepthr) atomicOr(&flags[idx >> 5], 1u << (idx & 31));
        }
    }
    if constexpr (!PATCHONLY) {
        if (fastB) {
            for (int c = tid; c < m; c += 256) {
                if (csim[c] > s31 + WIN) {
                    int idx = cand_idx[c];
                    atomicOr(&flags[idx >> 5], 1u << (idx & 31));
                }
            }
        }
    }
    __syncthreads();

    if constexpr (!PATCHONLY) {
#pragma unroll
        for (int s = 0; s < 10; ++s) {
            int e = 4 * tid + 1024 * s;
            if (e >= n) continue;
            float vals[4] = {v[s * 4 + 0], v[s * 4 + 1], v[s * 4 + 2], v[s * 4 + 3]};
            float o[4];
#pragma unroll
            for (int j = 0; j < 4; ++j) {
                int q = e + j;
                bool keep = (flags[q >> 5] >> (q & 31)) & 1u;
                o[j] = (keep && vals[j] > 0.0f) ? vals[j] : 0.0f;
            }
            *(float4*)(outp + e) = make_float4(o[0], o[1], o[2], o[3]);
        }
        __syncthreads();
    }

    if (fastB) {
        for (int c = tid; c < m; c += 256)
            if (csim[c] > s31 + WIN) outp[cand_idx[c]] = fmaxf(csim[c], 0.0f);
        for (int s2 = tid; s2 < mm; s2 += 256)
            if (rankarr[s2] < kneed)
                outp[cand_idx[blist[s2]]] = (float)fmax(cand_val[s2], 0.0);
    } else {
        for (int s2 = tid; s2 < mm; s2 += 256)
            if (rankarr[s2] < KSEL)
                outp[cand_idx[selc[s2]]] = (float)fmax(cand_val[s2], 0.0);
    }
}

extern "C" void kernel_launch(void* const* d_in, const int* in_sizes, int n_in,
                              void* d_out, int out_size, void* d_ws, size_t ws_size,
                              hipStream_t stream) {
    const float* F  = (const float*)d_in[0];
    const float* w0 = (const float*)d_in[1];
    const float* w1 = (const float*)d_in[2];
    float* out = (float*)d_out;
    int isz = in_sizes[1];           // 256
    int n = in_sizes[0] / isz;       // 10000

    char* ws = (char*)d_ws;
    __hip_bfloat16* Ebf = (__hip_bfloat16*)ws;                       // 5.12 MB
    double* snorm = (double*)(ws + (size_t)n * ISZ * 2);             // 80 KB
    size_t o_sim = (((size_t)n * ISZ * 2 + (size_t)n * 8) + 255) & ~(size_t)255;
    size_t need = o_sim + (size_t)n * n * 4;                         // +400 MB

    int nt = (n + 127) / 128;
    emb_kernel<<<n, 256, 0, stream>>>(F, w0, w1, Ebf, snorm, n);
    if (ws_size >= need) {
        float* S = (float*)(ws + o_sim);
        size_t n4 = ((size_t)n * n) / 4;   // n*n % 4 == 0
        zero_out<<<2048, 256, 0, stream>>>((float4*)out, n4);
        gemm_mfma<<<dim3(nt, nt), 256, 0, stream>>>(Ebf, S, n);
        topk_mask<true><<<n, 256, 0, stream>>>(S, out, F, w0, w1, snorm, n);
    } else {
        gemm_mfma<<<dim3(nt, nt), 256, 0, stream>>>(Ebf, out, n);
        topk_mask<false><<<n, 256, 0, stream>>>(out, out, F, w0, w1, snorm, n);
    }
}

// Round 21
// 388.666 us; speedup vs baseline: 1.0977x; 1.0977x over previous
//
#include <hip/hip_runtime.h>
#include <hip/hip_bf16.h>
#include <math.h>

#define ISZ 256
#define KSEL 31      // keep top-(K+1) = 31
#define CMIN 64      // min candidate count
#define CEXIT 192    // bisection-fallback window top
#define NCAND 320    // candidate cap
#define NSEL 64      // slow-path fp64 prefilter size
#define NBL 64       // borderline cap
#define WIN 4e-3f    // borderline half-width (>= 2x stored-sim error)
#define ZSTAT 2.25f  // thr = mean + ZSTAT*sd (~120 cands)

typedef __attribute__((ext_vector_type(8))) short bf16x8;
typedef __attribute__((ext_vector_type(4))) float f32x4;

__device__ __forceinline__ double h64_of(float f, float w0, float w1) {
    return fmax((double)f * (double)w0, 0.0) * (double)w1;
}

// ---------------- embedding (proven verbatim) ----------------
__global__ __launch_bounds__(256) void emb_kernel(const float* __restrict__ F,
                                                  const float* __restrict__ w0,
                                                  const float* __restrict__ w1,
                                                  __hip_bfloat16* __restrict__ Eb,
                                                  double* __restrict__ snorm,
                                                  int n) {
    int row = blockIdx.x;
    int t = threadIdx.x;
    float f = F[(size_t)row * ISZ + t];
    double h64 = h64_of(f, w0[t], w1[t]);
    double ss = h64 * h64;
#pragma unroll
    for (int off = 32; off; off >>= 1) ss += __shfl_down(ss, off);
    __shared__ double red[4];
    if ((t & 63) == 0) red[t >> 6] = ss;
    __syncthreads();
    double tot = red[0] + red[1] + red[2] + red[3];
    double s = fmax(sqrt(tot), 1e-12);
    if (t == 0) snorm[row] = s;
    Eb[(size_t)row * ISZ + t] = __float2bfloat16((float)(h64 / s));
}

// ---------------- symmetric MFMA gemm (R17/R19 proven, verbatim) ----------------
__global__ __launch_bounds__(256) void gemm_mfma(const __hip_bfloat16* __restrict__ Eb,
                                                 float* __restrict__ S, int n) {
    int bx = blockIdx.x, by = blockIdx.y;
    if (bx < by) return;
    __shared__ float lds[4][64][65];
    int row0 = by * 128, col0 = bx * 128;
    int tid = threadIdx.x, lane = tid & 63, wid = tid >> 6;
    int wr = wid >> 1, wc = wid & 1;
    int rbase = row0 + wr * 64 + (lane & 15);
    int cbase = col0 + wc * 64 + (lane & 15);
    int kg2 = ((lane >> 4) * 8) * 2;
    const char* Ep = (const char*)Eb;
    unsigned aoff[4], boff[4];
#pragma unroll
    for (int i = 0; i < 4; ++i) {
        aoff[i] = (unsigned)min(rbase + i * 16, n - 1) * (ISZ * 2) + kg2;
        boff[i] = (unsigned)min(cbase + i * 16, n - 1) * (ISZ * 2) + kg2;
    }
    f32x4 acc[4][4] = {};
#pragma unroll
    for (int kt = 0; kt < ISZ; kt += 32) {
        bf16x8 a[4], b[4];
#pragma unroll
        for (int i = 0; i < 4; ++i) a[i] = *(const bf16x8*)(Ep + aoff[i] + kt * 2);
#pragma unroll
        for (int j = 0; j < 4; ++j) b[j] = *(const bf16x8*)(Ep + boff[j] + kt * 2);
#pragma unroll
        for (int i = 0; i < 4; ++i)
#pragma unroll
            for (int j = 0; j < 4; ++j)
                acc[i][j] = __builtin_amdgcn_mfma_f32_16x16x32_bf16(a[i], b[j], acc[i][j], 0, 0, 0);
    }
    float (*T)[65] = lds[wid];   // wave-private
#pragma unroll
    for (int i = 0; i < 4; ++i)
#pragma unroll
        for (int j = 0; j < 4; ++j)
#pragma unroll
            for (int r = 0; r < 4; ++r)
                T[(lane >> 4) * 4 + i * 16 + r][(lane & 15) + j * 16] = acc[i][j][r];
    int gr0 = row0 + wr * 64;
    int gc0 = col0 + wc * 64;
    int c4 = (lane & 15) * 4;
#pragma unroll
    for (int p = 0; p < 16; ++p) {
        int r = p * 4 + (lane >> 4);
        int gr = gr0 + r;
        if (gr >= n) continue;
        int gc = gc0 + c4;
        float4 w = make_float4(T[r][c4], T[r][c4 + 1], T[r][c4 + 2], T[r][c4 + 3]);
        if (gc + 3 < n) {
            *(float4*)&S[(size_t)gr * n + gc] = w;
        } else {
            float wa[4] = {w.x, w.y, w.z, w.w};
#pragma unroll
            for (int q = 0; q < 4; ++q)
                if (gc + q < n) S[(size_t)gr * n + gc + q] = wa[q];
        }
    }
    if (bx > by) {
#pragma unroll
        for (int p = 0; p < 16; ++p) {
            int rp = p * 4 + (lane >> 4);
            int gr2 = gc0 + rp;
            if (gr2 >= n) continue;
            int gc2 = gr0 + c4;
            float4 w = make_float4(T[c4][rp], T[c4 + 1][rp], T[c4 + 2][rp], T[c4 + 3][rp]);
            if (gc2 + 3 < n) {
                *(float4*)&S[(size_t)gr2 * n + gc2] = w;
            } else {
                float wa[4] = {w.x, w.y, w.z, w.w};
#pragma unroll
                for (int q = 0; q < 4; ++q)
                    if (gc2 + q < n) S[(size_t)gr2 * n + gc2 + q] = wa[q];
            }
        }
    }
}

// R19-proven topk + fused row zeroing: zeros issue right after the row load
// (independent buffers -> overlap all candidate phases); patches after barrier.
// ZEROFILL=true: sims in ws, this kernel writes the zeros (no pre-zero pass).
template <bool ZEROFILL>
__global__ __launch_bounds__(256) void topk_mask(const float* SIM, float* OUT,
                                                 const float* __restrict__ F,
                                                 const float* __restrict__ W0,
                                                 const float* __restrict__ W1,
                                                 const double* __restrict__ snorm,
                                                 int n) {
    __shared__ unsigned flags[320];
    __shared__ float redf[8];
    __shared__ int redi[4];
    __shared__ int cand_idx[NCAND];
    __shared__ float csim[NCAND];
    __shared__ int selc[NSEL];
    __shared__ int blist[NBL];
    __shared__ double cand_val[NSEL];
    __shared__ int rankarr[NSEL];
    __shared__ int ncand, nhi_s, nbl_s;
    __shared__ float s31_s;
    int row = blockIdx.x;
    int tid = threadIdx.x;
    int lane = tid & 63, wid = tid >> 6;
    const float* simp = SIM + (size_t)row * n;
    float* outp = OUT + (size_t)row * n;

    float v[40];
#pragma unroll
    for (int s = 0; s < 10; ++s) {
        int e = 4 * tid + 1024 * s;
        if (e < n) {
            float4 w = *(const float4*)(simp + e);
            v[s * 4 + 0] = w.x; v[s * 4 + 1] = w.y;
            v[s * 4 + 2] = w.z; v[s * 4 + 3] = w.w;
        } else {
#pragma unroll
            for (int q = 0; q < 4; ++q) v[s * 4 + q] = -1e30f;
        }
    }
    if constexpr (ZEROFILL) {
        // independent of the SIM loads above -> overlaps all later phases
        float4 z4 = make_float4(0.f, 0.f, 0.f, 0.f);
#pragma unroll
        for (int s = 0; s < 10; ++s) {
            int e = 4 * tid + 1024 * s;
            if (e < n) *(float4*)(outp + e) = z4;
        }
    }
    if constexpr (!ZEROFILL)
        for (int q = tid; q < 320; q += 256) flags[q] = 0;
    if (tid == 0) { ncand = 0; nhi_s = 0; nbl_s = 0; }
    __syncthreads();

    {
        float s1 = 0.0f, s2 = 0.0f;
#pragma unroll
        for (int s = 0; s < 10; ++s) {
            int e = 4 * tid + 1024 * s;
            if (e < n) {
#pragma unroll
                for (int j = 0; j < 4; ++j) { float x = v[s * 4 + j]; s1 += x; s2 += x * x; }
            }
        }
#pragma unroll
        for (int off = 32; off; off >>= 1) { s1 += __shfl_down(s1, off); s2 += __shfl_down(s2, off); }
        if (lane == 0) { redf[wid] = s1; redf[wid + 4] = s2; }
        __syncthreads();
        if (tid == 0) {
            float S1 = redf[0] + redf[1] + redf[2] + redf[3];
            float S2 = redf[4] + redf[5] + redf[6] + redf[7];
            float mean = S1 / (float)n;
            float var = fmaxf(S2 / (float)n - mean * mean, 1e-12f);
            s31_s = mean + ZSTAT * sqrtf(var);
        }
        __syncthreads();
    }
    float thr = s31_s;

    auto blockcount = [&](float t) -> int {
        int c = 0;
#pragma unroll
        for (int q = 0; q < 40; ++q) c += (v[q] >= t) ? 1 : 0;
#pragma unroll
        for (int off = 32; off; off >>= 1) c += __shfl_down(c, off);
        if (lane == 0) redi[wid] = c;
        __syncthreads();
        int tot = redi[0] + redi[1] + redi[2] + redi[3];
        __syncthreads();
        return tot;
    };
    auto collect = [&](float t) {
#pragma unroll
        for (int s = 0; s < 10; ++s) {
            int e = 4 * tid + 1024 * s;
#pragma unroll
            for (int j = 0; j < 4; ++j) {
                float x = v[s * 4 + j];
                if (x >= t) {
                    int pos = atomicAdd(&ncand, 1);
                    if (pos < NCAND) { cand_idx[pos] = e + j; csim[pos] = x; }
                }
            }
        }
        __syncthreads();
    };

    collect(thr);
    if (ncand < CMIN || ncand > NCAND) {
        __syncthreads();
        if (tid == 0) ncand = 0;
        __syncthreads();
        float lo = 0.0f, hi = 0.75f;
        thr = 0.0f;
        bool found = false;
        for (int it = 0; it < 30 && !found; ++it) {
            float mid = 0.5f * (lo + hi);
            int c = blockcount(mid);
            if (c >= CMIN && c <= CEXIT) { thr = mid; found = true; }
            else if (c >= CMIN) lo = mid;
            else hi = mid;
        }
        if (!found) thr = lo;
        collect(thr);
    }
    int m = min(ncand, NCAND);

    for (int c = tid; c < m; c += 256) {
        float mys = csim[c]; int myi = cand_idx[c]; int r = 0;
        for (int j = 0; j < m; ++j) {
            float vj = csim[j];
            r += (vj > mys || (vj == mys && cand_idx[j] < myi)) ? 1 : 0;
        }
        if (r < NSEL) selc[r] = c;
        if (r == KSEL - 1) s31_s = mys;
    }
    __syncthreads();
    float s31 = s31_s;

    for (int c = tid; c < m; c += 256) {
        float sc = csim[c];
        if (sc > s31 + WIN) atomicAdd(&nhi_s, 1);
        else if (sc >= s31 - WIN) { int p = atomicAdd(&nbl_s, 1); if (p < NBL) blist[p] = c; }
    }
    __syncthreads();
    int nhi = nhi_s, nblv = nbl_s;
    bool fastB = (nblv <= NBL);
    int mm = fastB ? nblv : min(m, NSEL);
    int kneed = KSEL - nhi;

    double hr[4];
    float w0e[4], w1e[4];
#pragma unroll
    for (int r = 0; r < 4; ++r) {
        int e = lane + 64 * r;
        w0e[r] = W0[e];
        w1e[r] = W1[e];
        hr[r] = h64_of(F[(size_t)row * ISZ + e], w0e[r], w1e[r]);
    }
    double srow = snorm[row];
    for (int s = wid * 4; s < mm; s += 16) {
        int l0 = fastB ? blist[s] : selc[s];
        int l1 = fastB ? blist[min(s + 1, mm - 1)] : selc[min(s + 1, mm - 1)];
        int l2 = fastB ? blist[min(s + 2, mm - 1)] : selc[min(s + 2, mm - 1)];
        int l3 = fastB ? blist[min(s + 3, mm - 1)] : selc[min(s + 3, mm - 1)];
        int j0 = cand_idx[l0], j1 = cand_idx[l1], j2 = cand_idx[l2], j3 = cand_idx[l3];
        double a0 = 0.0, a1 = 0.0, a2 = 0.0, a3 = 0.0;
#pragma unroll
        for (int r = 0; r < 4; ++r) {
            int e = lane + 64 * r;
            float f0 = F[(size_t)j0 * ISZ + e];
            float f1 = F[(size_t)j1 * ISZ + e];
            float f2 = F[(size_t)j2 * ISZ + e];
            float f3 = F[(size_t)j3 * ISZ + e];
            a0 += hr[r] * h64_of(f0, w0e[r], w1e[r]);
            a1 += hr[r] * h64_of(f1, w0e[r], w1e[r]);
            a2 += hr[r] * h64_of(f2, w0e[r], w1e[r]);
            a3 += hr[r] * h64_of(f3, w0e[r], w1e[r]);
        }
#pragma unroll
        for (int off = 32; off; off >>= 1) {
            a0 += __shfl_down(a0, off);
            a1 += __shfl_down(a1, off);
            a2 += __shfl_down(a2, off);
            a3 += __shfl_down(a3, off);
        }
        if (lane == 0) {
            cand_val[s] = a0 / (srow * snorm[j0]);
            if (s + 1 < mm) cand_val[s + 1] = a1 / (srow * snorm[j1]);
            if (s + 2 < mm) cand_val[s + 2] = a2 / (srow * snorm[j2]);
            if (s + 3 < mm) cand_val[s + 3] = a3 / (srow * snorm[j3]);
        }
    }
    __syncthreads();

    int keepthr = fastB ? kneed : KSEL;
    for (int s2 = tid; s2 < mm; s2 += 256) {
        int li = fastB ? blist[s2] : selc[s2];
        double vv = cand_val[s2];
        int idx = cand_idx[li];
        int rank = 0;
        for (int j2 = 0; j2 < mm; ++j2) {
            int lj = fastB ? blist[j2] : selc[j2];
            double vj = cand_val[j2];
            rank += (vj > vv || (vj == vv && cand_idx[lj] < idx)) ? 1 : 0;
        }
        rankarr[s2] = rank;
        if constexpr (!ZEROFILL) {
            if (rank < keepthr) atomicOr(&flags[idx >> 5], 1u << (idx & 31));
        }
    }
    if constexpr (!ZEROFILL) {
        if (fastB) {
            for (int c = tid; c < m; c += 256) {
                if (csim[c] > s31 + WIN) {
                    int idx = cand_idx[c];
                    atomicOr(&flags[idx >> 5], 1u << (idx & 31));
                }
            }
        }
    }
    __syncthreads();   // zeros (ZEROFILL) or flags complete before patches

    if constexpr (!ZEROFILL) {
#pragma unroll
        for (int s = 0; s < 10; ++s) {
            int e = 4 * tid + 1024 * s;
            if (e >= n) continue;
            float vals[4] = {v[s * 4 + 0], v[s * 4 + 1], v[s * 4 + 2], v[s * 4 + 3]};
            float o[4];
#pragma unroll
            for (int j = 0; j < 4; ++j) {
                int q = e + j;
                bool keep = (flags[q >> 5] >> (q & 31)) & 1u;
                o[j] = (keep && vals[j] > 0.0f) ? vals[j] : 0.0f;
            }
            *(float4*)(outp + e) = make_float4(o[0], o[1], o[2], o[3]);
        }
        __syncthreads();
    }

    if (fastB) {
        for (int c = tid; c < m; c += 256)
            if (csim[c] > s31 + WIN) outp[cand_idx[c]] = fmaxf(csim[c], 0.0f);
        for (int s2 = tid; s2 < mm; s2 += 256)
            if (rankarr[s2] < kneed)
                outp[cand_idx[blist[s2]]] = (float)fmax(cand_val[s2], 0.0);
    } else {
        for (int s2 = tid; s2 < mm; s2 += 256)
            if (rankarr[s2] < KSEL)
                outp[cand_idx[selc[s2]]] = (float)fmax(cand_val[s2], 0.0);
    }
}

extern "C" void kernel_launch(void* const* d_in, const int* in_sizes, int n_in,
                              void* d_out, int out_size, void* d_ws, size_t ws_size,
                              hipStream_t stream) {
    const float* F  = (const float*)d_in[0];
    const float* w0 = (const float*)d_in[1];
    const float* w1 = (const float*)d_in[2];
    float* out = (float*)d_out;
    int isz = in_sizes[1];           // 256
    int n = in_sizes[0] / isz;       // 10000

    char* ws = (char*)d_ws;
    __hip_bfloat16* Ebf = (__hip_bfloat16*)ws;                       // 5.12 MB
    double* snorm = (double*)(ws + (size_t)n * ISZ * 2);             // 80 KB
    size_t o_sim = (((size_t)n * ISZ * 2 + (size_t)n * 8) + 255) & ~(size_t)255;
    size_t need = o_sim + (size_t)n * n * 4;                         // +400 MB

    int nt = (n + 127) / 128;
    emb_kernel<<<n, 256, 0, stream>>>(F, w0, w1, Ebf, snorm, n);
    if (ws_size >= need) {
        float* S = (float*)(ws + o_sim);
        gemm_mfma<<<dim3(nt, nt), 256, 0, stream>>>(Ebf, S, n);
        topk_mask<true><<<n, 256, 0, stream>>>(S, out, F, w0, w1, snorm, n);
    } else {
        gemm_mfma<<<dim3(nt, nt), 256, 0, stream>>>(Ebf, out, n);
        topk_mask<false><<<n, 256, 0, stream>>>(out, out, F, w0, w1, snorm, n);
    }
}